// Round 16
// baseline (531.368 us; speedup 1.0000x reference)
//
#include <hip/hip_runtime.h>
#include <stdint.h>

typedef unsigned short ushort_t;
typedef unsigned long long u64_t;
typedef __attribute__((ext_vector_type(4))) float f32x4;
typedef __attribute__((ext_vector_type(8))) short s16x8;

#define S1_ELEMS ((size_t)1568*64*512)   // 51,380,224 elements per q/k/v/x buffer

// ---------- bf16 helpers (RNE)
__device__ __forceinline__ ushort_t f2bf(float f) {
  unsigned u = __builtin_bit_cast(unsigned, f);
  u = u + 0x7fffu + ((u >> 16) & 1u);
  return (ushort_t)(u >> 16);
}

// ---------- async global->LDS, 16B per lane (dest = uniform base + lane*16)
__device__ __forceinline__ void gl_lds16(const ushort_t* g, ushort_t* l) {
  typedef __attribute__((address_space(1))) void gvoid;
  typedef __attribute__((address_space(3))) void lvoid;
  __builtin_amdgcn_global_load_lds((gvoid*)(ushort_t*)g, (lvoid*)l, 16, 0, 0);
}

// ---------- kernel 1: merged prep — x/wq/wp f32->bf16 convert + bias gather.
__global__ void k_prep(const float* __restrict__ x, ushort_t* __restrict__ xh,
                       const float* __restrict__ wq, ushort_t* __restrict__ wqh,
                       const float* __restrict__ wp, ushort_t* __restrict__ wph,
                       const float* __restrict__ table, const int* __restrict__ rel_idx,
                       float* __restrict__ bias) {
  int blk = blockIdx.x, tid = threadIdx.x;
  if (blk < 3136) {
    long i0 = (long)blk*256 + tid;
    #pragma unroll
    for (int rep = 0; rep < 8; rep++) {
      long i = i0 + (long)rep*802816;
      float4 v0 = ((const float4*)x)[2*i];
      float4 v1 = ((const float4*)x)[2*i + 1];
      s16x8 pk;
      pk[0] = (short)f2bf(v0.x); pk[1] = (short)f2bf(v0.y);
      pk[2] = (short)f2bf(v0.z); pk[3] = (short)f2bf(v0.w);
      pk[4] = (short)f2bf(v1.x); pk[5] = (short)f2bf(v1.y);
      pk[6] = (short)f2bf(v1.z); pk[7] = (short)f2bf(v1.w);
      *(s16x8*)&xh[i*8] = pk;
    }
  } else if (blk < 3648) {
    const float* src; ushort_t* dst; long i;
    if (blk < 3520) { src = wq; dst = wqh; i = (long)(blk - 3136)*256 + tid; }
    else            { src = wp; dst = wph; i = (long)(blk - 3520)*256 + tid; }
    float4 v0 = ((const float4*)src)[2*i];
    float4 v1 = ((const float4*)src)[2*i + 1];
    s16x8 pk;
    pk[0] = (short)f2bf(v0.x); pk[1] = (short)f2bf(v0.y);
    pk[2] = (short)f2bf(v0.z); pk[3] = (short)f2bf(v0.w);
    pk[4] = (short)f2bf(v1.x); pk[5] = (short)f2bf(v1.y);
    pk[6] = (short)f2bf(v1.z); pk[7] = (short)f2bf(v1.w);
    *(s16x8*)&dst[i*8] = pk;
  } else {
    int i0 = ((blk - 3648)*256 + tid)*4;     // 65536 total
    #pragma unroll
    for (int j = 0; j < 4; j++) {
      int i = i0 + j;
      int h = i >> 12, rc = i & 4095;
      bias[i] = table[rel_idx[rc] * 16 + h];
    }
  }
}

// ================= QKV GEMM: 128x256 tile, BK=32, 16 K-tiles, 8 waves (2x4),
// acc[4][4]=64 VGPR -> 2 blocks/CU (16 waves). Triple-buffered 24 KiB stages
// (72 KiB dynamic LDS), depth-2 counted vmcnt(3), ONE barrier per tile.
// Hazard derivation:
//  - RAW (tile t data ready): vmcnt(3) at iter t leaves only {t+1} in flight
//    (t staged at iter t-2, t+1 at iter t-1, 3 issues/wave each); barrier
//    publishes all waves' stages.
//  - WAR (stage t+2 overwrites buf[(t+2)%3] = buf[(t-1)%3]): stage is issued
//    AFTER barrier(t); any wave passing barrier(t) has executed MFMA(t-1),
//    whose operands force lgkmcnt completion of its tile-(t-1) ds_reads.
// K-order per acc element: t*32 sequential == r12's kh0/kh1 order -> bit-identical.
__global__ __launch_bounds__(512, 4) void k_gemm_qkv(
    const ushort_t* __restrict__ xh, const ushort_t* __restrict__ wh,
    ushort_t* __restrict__ qh, ushort_t* __restrict__ kh, ushort_t* __restrict__ vt) {
  extern __shared__ __align__(16) ushort_t lds[];   // 3 bufs x 12288 ushort
  const int tid = threadIdx.x, w = tid >> 6, lane = tid & 63;
  const int g = lane >> 4, l15 = lane & 15;
  const int wm = w >> 2, wn = w & 3;
  int flat = blockIdx.x;                 // 4704 = 8*588, bijective XCD swizzle
  int swz = (flat & 7) * 588 + (flat >> 3);
  int bx = swz % 6, by = swz / 6;        // bx fastest -> A-panel L2 reuse per XCD

  // wave w stages: A subtile w (1 KiB), B subtiles 2w, 2w+1
  const ushort_t* pA  = xh + ((size_t)(by*128 + w*16 + l15))*512 + g*8;
  const ushort_t* pB0 = wh + ((size_t)(bx*256 + (2*w)*16 + l15))*512 + g*8;
  const ushort_t* pB1 = pB0 + 16*512;

  f32x4 acc[4][4];
  #pragma unroll
  for (int r = 0; r < 4; r++)
    #pragma unroll
    for (int c = 0; c < 4; c++) acc[r][c] = (f32x4){0.f, 0.f, 0.f, 0.f};

  // prologue: tiles 0,1 into bufs 0,1 (3 issues/wave each)
  #pragma unroll
  for (int t0 = 0; t0 < 2; t0++) {
    ushort_t* buf = lds + t0*12288;
    gl_lds16(pA  + t0*32, buf + w*512);
    gl_lds16(pB0 + t0*32, buf + 4096 + (2*w)*512);
    gl_lds16(pB1 + t0*32, buf + 4096 + (2*w + 1)*512);
  }

  #pragma unroll
  for (int t = 0; t < 16; ++t) {
    if (t == 15) asm volatile("s_waitcnt vmcnt(0)" ::: "memory");
    else         asm volatile("s_waitcnt vmcnt(3)" ::: "memory");
    __builtin_amdgcn_s_barrier();
    if (t < 14) {                        // stage tile t+2 (issued post-barrier)
      ushort_t* bufS = lds + ((t + 2) % 3)*12288;
      gl_lds16(pA  + (t + 2)*32, bufS + w*512);
      gl_lds16(pB0 + (t + 2)*32, bufS + 4096 + (2*w)*512);
      gl_lds16(pB1 + (t + 2)*32, bufS + 4096 + (2*w + 1)*512);
    }
    ushort_t* buf = lds + (t % 3)*12288;
    s16x8 af[4], bf[4];
    #pragma unroll
    for (int ta = 0; ta < 4; ta++)
      af[ta] = *(const s16x8*)&buf[(wm*4 + ta)*512 + lane*8];
    #pragma unroll
    for (int tb = 0; tb < 4; tb++)
      bf[tb] = *(const s16x8*)&buf[4096 + (wn*4 + tb)*512 + lane*8];
    __builtin_amdgcn_s_setprio(1);
    #pragma unroll
    for (int ta = 0; ta < 4; ta++)
      #pragma unroll
      for (int tb = 0; tb < 4; tb++)
        acc[ta][tb] = __builtin_amdgcn_mfma_f32_16x16x32_bf16(af[ta], bf[tb], acc[ta][tb], 0, 0, 0);
    __builtin_amdgcn_s_setprio(0);
  }

  // ---- epilogue: 2 passes of 64 rows (8 regions x 4 KiB = 32 KiB), r11 swizzles.
  // bx: 0,1->q  2,3->k  4,5->v(T)
  __builtin_amdgcn_s_barrier();          // all waves' tile-15 reads consumed
  const int sel = bx >> 1;
  ushort_t* dst = (sel == 0) ? qh : (sel == 1) ? kh : vt;
  const int hbase = (bx & 1) * 8;
  #pragma unroll
  for (int p = 0; p < 2; p++) {
    if (p) { asm volatile("" ::: "memory"); __builtin_amdgcn_s_barrier(); }
    if (wm == p) {
      if (sel < 2) {
        #pragma unroll
        for (int ta = 0; ta < 4; ta++)
          #pragma unroll
          for (int tb = 0; tb < 4; tb++)
            #pragma unroll
            for (int j = 0; j < 4; j++) {
              int n = ta*16 + g*4 + j;           // local row 0..63
              int lc = wn*64 + tb*16 + l15;      // local col 0..255
              int r = lc >> 5, d = lc & 31;
              int byte = r*4096 + ((n*64 + d*2) ^ ((n & 12) << 3));
              *(ushort_t*)((char*)lds + byte) = f2bf(acc[ta][tb][j]);
            }
      } else {
        #pragma unroll
        for (int ta = 0; ta < 4; ta++)
          #pragma unroll
          for (int tb = 0; tb < 4; tb++) {
            int n0 = ta*16 + g*4;
            int lc = wn*64 + tb*16 + l15;
            int r = lc >> 5, d = lc & 31;
            u64_t pk = (u64_t)f2bf(acc[ta][tb][0])
                     | ((u64_t)f2bf(acc[ta][tb][1]) << 16)
                     | ((u64_t)f2bf(acc[ta][tb][2]) << 32)
                     | ((u64_t)f2bf(acc[ta][tb][3]) << 48);
            int byte = r*4096 + ((d*128 + n0*2) ^ ((d & 7) << 4) ^ (((((d >> 3) ^ (n0 >> 3))) & 1) << 6));
            *(u64_t*)((char*)lds + byte) = pk;
          }
      }
    }
    asm volatile("s_waitcnt lgkmcnt(0)" ::: "memory");
    __builtin_amdgcn_s_barrier();
    #pragma unroll
    for (int it = 0; it < 4; it++) {
      int cg = it*512 + tid;               // 0..2047
      int r = cg >> 8, inner = cg & 255;
      int byte;
      if (sel < 2) byte = r*4096 + ((inner*16) ^ (((inner >> 2) & 12) << 3));
      else         byte = r*4096 + ((inner*16) ^ (((inner >> 3) & 7) << 4) ^ ((((inner >> 6) ^ inner) & 1) << 6));
      s16x8 v = *(const s16x8*)((const char*)lds + byte);
      int b = by*2 + p, h = hbase + r;
      *(s16x8*)&dst[(size_t)(b*16 + h)*2048 + inner*8] = v;
    }
  }
}

// ================= shared 256x256 BK=64 loop (proj; r11 structure).
__device__ __forceinline__ void gemm256_loop(
    ushort_t* lds, const ushort_t* pA, const ushort_t* pB,
    int w, int lane, int wm, int wn, f32x4 (&acc)[8][4]) {
  #pragma unroll
  for (int q = 0; q < 2; q++) {
    gl_lds16(pA + q*8192 +  0, lds + ((2*w + q)*2 + 0)*512);
    gl_lds16(pA + q*8192 + 32, lds + ((2*w + q)*2 + 1)*512);
    gl_lds16(pB + q*8192 +  0, lds + 16384 + ((2*w + q)*2 + 0)*512);
    gl_lds16(pB + q*8192 + 32, lds + 16384 + ((2*w + q)*2 + 1)*512);
  }
  asm volatile("s_waitcnt vmcnt(0)" ::: "memory");
  __builtin_amdgcn_s_barrier();

  for (int tau = 0; tau < 8; ++tau) {
    ushort_t* bufR = lds + (tau & 1)*32768;
    ushort_t* bufW = lds + ((tau & 1) ^ 1)*32768;
    if (tau < 7) {
      int ko = (tau + 1)*64;
      #pragma unroll
      for (int q = 0; q < 2; q++) {
        gl_lds16(pA + q*8192 + ko,      bufW + ((2*w + q)*2 + 0)*512);
        gl_lds16(pA + q*8192 + ko + 32, bufW + ((2*w + q)*2 + 1)*512);
        gl_lds16(pB + q*8192 + ko,      bufW + 16384 + ((2*w + q)*2 + 0)*512);
        gl_lds16(pB + q*8192 + ko + 32, bufW + 16384 + ((2*w + q)*2 + 1)*512);
      }
    }
    s16x8 af[4][2], bf[4][2];
    #pragma unroll
    for (int t = 0; t < 4; t++)
      #pragma unroll
      for (int kh = 0; kh < 2; kh++) {
        af[t][kh] = *(const s16x8*)&bufR[((wm*8 + t)*2 + kh)*512 + lane*8];
        bf[t][kh] = *(const s16x8*)&bufR[16384 + ((wn*4 + t)*2 + kh)*512 + lane*8];
      }
    __builtin_amdgcn_s_barrier();
    asm volatile("s_waitcnt lgkmcnt(0)" ::: "memory");
    __builtin_amdgcn_sched_barrier(0);
    __builtin_amdgcn_s_setprio(1);
    #pragma unroll
    for (int t = 0; t < 4; t++)
      #pragma unroll
      for (int tb = 0; tb < 4; tb++) {
        acc[t][tb] = __builtin_amdgcn_mfma_f32_16x16x32_bf16(af[t][0], bf[tb][0], acc[t][tb], 0, 0, 0);
        acc[t][tb] = __builtin_amdgcn_mfma_f32_16x16x32_bf16(af[t][1], bf[tb][1], acc[t][tb], 0, 0, 0);
      }
    __builtin_amdgcn_s_setprio(0);
    s16x8 ag[4][2];
    #pragma unroll
    for (int t = 0; t < 4; t++)
      #pragma unroll
      for (int kh = 0; kh < 2; kh++)
        ag[t][kh] = *(const s16x8*)&bufR[((wm*8 + 4 + t)*2 + kh)*512 + lane*8];
    asm volatile("s_waitcnt lgkmcnt(0)" ::: "memory");
    __builtin_amdgcn_sched_barrier(0);
    __builtin_amdgcn_s_setprio(1);
    #pragma unroll
    for (int t = 0; t < 4; t++)
      #pragma unroll
      for (int tb = 0; tb < 4; tb++) {
        acc[4 + t][tb] = __builtin_amdgcn_mfma_f32_16x16x32_bf16(ag[t][0], bf[tb][0], acc[4 + t][tb], 0, 0, 0);
        acc[4 + t][tb] = __builtin_amdgcn_mfma_f32_16x16x32_bf16(ag[t][1], bf[tb][1], acc[4 + t][tb], 0, 0, 0);
      }
    __builtin_amdgcn_s_setprio(0);
    asm volatile("s_waitcnt vmcnt(0)" ::: "memory");
    __builtin_amdgcn_s_barrier();
  }
}

// ================= proj GEMM: 256x256, f32 2-pass swizzled epilogue (r11 config).
__global__ __launch_bounds__(512, 2) void k_gemm_proj(
    const ushort_t* __restrict__ ah, const ushort_t* __restrict__ wh,
    const float* __restrict__ pb, float* __restrict__ out) {
  extern __shared__ __align__(16) ushort_t lds[];
  const int tid = threadIdx.x, w = tid >> 6, lane = tid & 63;
  const int g = lane >> 4, l15 = lane & 15;
  const int wm = w >> 2, wn = w & 3;
  int flat = blockIdx.x;                 // 784 = 8*98, bijective XCD swizzle
  int swz = (flat & 7) * 98 + (flat >> 3);
  int bx = swz & 1, by = swz >> 1;

  const ushort_t* pA = ah + ((size_t)by*256 + (size_t)(2*w)*16 + l15)*512 + g*8;
  const ushort_t* pB = wh + ((size_t)bx*256 + (size_t)(2*w)*16 + l15)*512 + g*8;

  f32x4 acc[8][4];
  #pragma unroll
  for (int r = 0; r < 8; r++)
    #pragma unroll
    for (int c = 0; c < 4; c++) acc[r][c] = (f32x4){0.f, 0.f, 0.f, 0.f};

  gemm256_loop(lds, pA, pB, w, lane, wm, wn, acc);

  asm volatile("" ::: "memory");
  #pragma unroll
  for (int p = 0; p < 2; p++) {
    if (p) { asm volatile("" ::: "memory"); __builtin_amdgcn_s_barrier(); }
    if (wm == p) {
      #pragma unroll
      for (int ra = 0; ra < 8; ra++)
        #pragma unroll
        for (int tb = 0; tb < 4; tb++)
          #pragma unroll
          for (int j = 0; j < 4; j++) {
            int row = ra*16 + g*4 + j;          // local 0-127
            int col = wn*64 + tb*16 + l15;
            int byte = (row*1024 + col*4) ^ ((row & 12) << 2) ^ ((row & 8) << 3);
            *(float*)((char*)lds + byte) = acc[ra][tb][j];
          }
    }
    asm volatile("s_waitcnt lgkmcnt(0)" ::: "memory");
    __builtin_amdgcn_s_barrier();
    #pragma unroll
    for (int it = 0; it < 16; it++) {
      int cg = it*512 + tid;
      int row = cg >> 6, c16 = cg & 63;
      int byte = row*1024 + ((c16*16) ^ ((row & 12) << 2) ^ ((row & 8) << 3));
      f32x4 v = *(const f32x4*)((const char*)lds + byte);
      int ncol = bx*256 + c16*4;
      f32x4 pbv = *(const f32x4*)&pb[ncol];
      v = v + pbv;
      *(f32x4*)&out[(size_t)(by*256 + p*128 + row)*512 + ncol] = v;
    }
  }
}

// ---------- kernel 3: attention (r15 config: fragment-linear P, 3 blocks/CU).
__global__ __launch_bounds__(256) void k_attn(
    const ushort_t* __restrict__ qh, const ushort_t* __restrict__ kh,
    const ushort_t* __restrict__ vt, const float* __restrict__ bias,
    ushort_t* __restrict__ aoh) {
  __shared__ ushort_t plds[4][4096];       // fragment-linear P, per wave
  __shared__ float blds[64*68];            // pitch 68 -> only free 2-way conflicts
  const int tid = threadIdx.x, w = tid >> 6, lane = tid & 63;
  const int g = lane >> 4, l15 = lane & 15;
  const int h = blockIdx.x & 15;
  const int b = (blockIdx.x >> 4)*4 + w;   // 392 b-groups x 16 heads
  const size_t base = (size_t)(b*16 + h) * 2048;

  s16x8 qf[4], kf[4];
  #pragma unroll
  for (int t = 0; t < 4; t++) {
    size_t o = base + (size_t)(t*16 + l15)*32 + g*8;
    qf[t] = *(const s16x8*)&qh[o];
    kf[t] = *(const s16x8*)&kh[o];
  }
  s16x8 vf[2][2];
  #pragma unroll
  for (int kt = 0; kt < 2; kt++)
    #pragma unroll
    for (int nt = 0; nt < 2; nt++)
      vf[kt][nt] = *(const s16x8*)&vt[base + (size_t)(nt*16 + l15)*64 + kt*32 + g*8];

  const float* bh_ = bias + ((size_t)h << 12);
  #pragma unroll
  for (int it = 0; it < 4; it++) {
    int idx = it*1024 + tid*4;
    int rr = idx >> 6, cc = idx & 63;
    *(f32x4*)&blds[rr*68 + cc] = *(const f32x4*)&bh_[idx];
  }
  __syncthreads();

  f32x4 s[4][4];
  #pragma unroll
  for (int r = 0; r < 4; r++)
    #pragma unroll
    for (int c = 0; c < 4; c++) s[r][c] = (f32x4){0.f,0.f,0.f,0.f};
  #pragma unroll
  for (int r = 0; r < 4; r++)
    #pragma unroll
    for (int c = 0; c < 4; c++)
      s[r][c] = __builtin_amdgcn_mfma_f32_16x16x32_bf16(qf[r], kf[c], s[r][c], 0, 0, 0);

  const float invs = 0.17677669529663687f;  // 1/sqrt(32)
  #pragma unroll
  for (int r = 0; r < 4; r++)
    #pragma unroll
    for (int c = 0; c < 4; c++)
      #pragma unroll
      for (int j = 0; j < 4; j++) {
        int rr = r*16 + g*4 + j, cc = c*16 + l15;
        s[r][c][j] = s[r][c][j]*invs + blds[rr*68 + cc];
      }

  #pragma unroll
  for (int r = 0; r < 4; r++)
    #pragma unroll
    for (int j = 0; j < 4; j++) {
      float mx = fmaxf(fmaxf(s[r][0][j], s[r][1][j]), fmaxf(s[r][2][j], s[r][3][j]));
      mx = fmaxf(mx, __shfl_xor(mx, 1));
      mx = fmaxf(mx, __shfl_xor(mx, 2));
      mx = fmaxf(mx, __shfl_xor(mx, 4));
      mx = fmaxf(mx, __shfl_xor(mx, 8));
      float p0 = __expf(s[r][0][j]-mx), p1 = __expf(s[r][1][j]-mx);
      float p2 = __expf(s[r][2][j]-mx), p3 = __expf(s[r][3][j]-mx);
      float sum = p0 + p1 + p2 + p3;
      sum += __shfl_xor(sum, 1);
      sum += __shfl_xor(sum, 2);
      sum += __shfl_xor(sum, 4);
      sum += __shfl_xor(sum, 8);
      float rv = 1.0f / sum;
      s[r][0][j] = p0*rv; s[r][1][j] = p1*rv; s[r][2][j] = p2*rv; s[r][3][j] = p3*rv;
    }

  ushort_t* Pw = plds[w];
  asm volatile("s_waitcnt lgkmcnt(0)" ::: "memory");
  __builtin_amdgcn_sched_barrier(0);
  #pragma unroll
  for (int r = 0; r < 4; r++)
    #pragma unroll
    for (int c = 0; c < 4; c++)
      #pragma unroll
      for (int j = 0; j < 4; j++) {
        int idx = ((c >> 1)*4 + r)*512 + ((((c & 1)*2) + (l15 >> 3))*16 + g*4 + j)*8 + (l15 & 7);
        Pw[idx] = f2bf(s[r][c][j]);
      }
  asm volatile("s_waitcnt lgkmcnt(0)" ::: "memory");
  __builtin_amdgcn_sched_barrier(0);

  s16x8 pf[4][2];
  #pragma unroll
  for (int ta = 0; ta < 4; ta++)
    #pragma unroll
    for (int kt = 0; kt < 2; kt++)
      pf[ta][kt] = *(const s16x8*)&Pw[(kt*4 + ta)*512 + lane*8];

  f32x4 o[4][2];
  #pragma unroll
  for (int ta = 0; ta < 4; ta++)
    #pragma unroll
    for (int nt = 0; nt < 2; nt++) o[ta][nt] = (f32x4){0.f,0.f,0.f,0.f};
  #pragma unroll
  for (int ta = 0; ta < 4; ta++)
    #pragma unroll
    for (int nt = 0; nt < 2; nt++)
      #pragma unroll
      for (int kt = 0; kt < 2; kt++)
        o[ta][nt] = __builtin_amdgcn_mfma_f32_16x16x32_bf16(pf[ta][kt], vf[kt][nt], o[ta][nt], 0, 0, 0);

  #pragma unroll
  for (int ta = 0; ta < 4; ta++)
    #pragma unroll
    for (int nt = 0; nt < 2; nt++)
      #pragma unroll
      for (int j = 0; j < 4; j++) {
        int rr = ta*16 + g*4 + j, dd = nt*16 + l15;
        aoh[((size_t)b*64 + rr)*512 + h*32 + dd] = f2bf(o[ta][nt][j]);
      }
}

extern "C" void kernel_launch(void* const* d_in, const int* in_sizes, int n_in,
                              void* d_out, int out_size, void* d_ws, size_t ws_size,
                              hipStream_t stream) {
  const float* x      = (const float*)d_in[0];
  const float* qkv_w  = (const float*)d_in[1];
  const float* table  = (const float*)d_in[2];
  const float* proj_w = (const float*)d_in[3];
  const float* proj_b = (const float*)d_in[4];
  const int*   rel_idx = (const int*)d_in[5];

  const size_t S1 = S1_ELEMS;
  const size_t need = (4*S1 + 786432 + 262144)*sizeof(ushort_t) + 65536*sizeof(float);
  if (ws_size < need) return;

  ushort_t* qh  = (ushort_t*)d_ws;
  ushort_t* kh  = qh + S1;
  ushort_t* vt  = kh + S1;
  ushort_t* xh  = vt + S1;        // reused as attention-out after QKV GEMM
  ushort_t* wqh = xh + S1;
  ushort_t* wph = wqh + 786432;
  float*    bias = (float*)(wph + 262144);
  ushort_t* aoh = xh;

  hipFuncSetAttribute((const void*)k_gemm_qkv,
                      hipFuncAttributeMaxDynamicSharedMemorySize, 73728);
  hipFuncSetAttribute((const void*)k_gemm_proj,
                      hipFuncAttributeMaxDynamicSharedMemorySize, 131072);

  k_prep<<<3712, 256, 0, stream>>>(x, xh, qkv_w, wqh, proj_w, wph, table, rel_idx, bias);
  k_gemm_qkv<<<4704, 512, 73728, stream>>>(xh, wqh, qh, kh, vt);
  k_attn<<<6272, 256, 0, stream>>>(qh, kh, vt, bias, aoh);
  k_gemm_proj<<<784, 512, 131072, stream>>>(aoh, wph, proj_b, (float*)d_out);
}

// Round 17
// 508.046 us; speedup vs baseline: 1.0459x; 1.0459x over previous
//
#include <hip/hip_runtime.h>
#include <stdint.h>

typedef unsigned short ushort_t;
typedef unsigned long long u64_t;
typedef __attribute__((ext_vector_type(4))) float f32x4;
typedef __attribute__((ext_vector_type(8))) short s16x8;

#define S1_ELEMS ((size_t)1568*64*512)   // 51,380,224 elements per q/k/v/x buffer

// ---------- bf16 helpers (RNE)
__device__ __forceinline__ ushort_t f2bf(float f) {
  unsigned u = __builtin_bit_cast(unsigned, f);
  u = u + 0x7fffu + ((u >> 16) & 1u);
  return (ushort_t)(u >> 16);
}

// ---------- async global->LDS, 16B per lane (dest = uniform base + lane*16)
__device__ __forceinline__ void gl_lds16(const ushort_t* g, ushort_t* l) {
  typedef __attribute__((address_space(1))) void gvoid;
  typedef __attribute__((address_space(3))) void lvoid;
  __builtin_amdgcn_global_load_lds((gvoid*)(ushort_t*)g, (lvoid*)l, 16, 0, 0);
}

// ---------- kernel 1: merged prep — x/wq/wp f32->bf16 convert + bias gather.
__global__ void k_prep(const float* __restrict__ x, ushort_t* __restrict__ xh,
                       const float* __restrict__ wq, ushort_t* __restrict__ wqh,
                       const float* __restrict__ wp, ushort_t* __restrict__ wph,
                       const float* __restrict__ table, const int* __restrict__ rel_idx,
                       float* __restrict__ bias) {
  int blk = blockIdx.x, tid = threadIdx.x;
  if (blk < 3136) {
    long i0 = (long)blk*256 + tid;
    #pragma unroll
    for (int rep = 0; rep < 8; rep++) {
      long i = i0 + (long)rep*802816;
      float4 v0 = ((const float4*)x)[2*i];
      float4 v1 = ((const float4*)x)[2*i + 1];
      s16x8 pk;
      pk[0] = (short)f2bf(v0.x); pk[1] = (short)f2bf(v0.y);
      pk[2] = (short)f2bf(v0.z); pk[3] = (short)f2bf(v0.w);
      pk[4] = (short)f2bf(v1.x); pk[5] = (short)f2bf(v1.y);
      pk[6] = (short)f2bf(v1.z); pk[7] = (short)f2bf(v1.w);
      *(s16x8*)&xh[i*8] = pk;
    }
  } else if (blk < 3648) {
    const float* src; ushort_t* dst; long i;
    if (blk < 3520) { src = wq; dst = wqh; i = (long)(blk - 3136)*256 + tid; }
    else            { src = wp; dst = wph; i = (long)(blk - 3520)*256 + tid; }
    float4 v0 = ((const float4*)src)[2*i];
    float4 v1 = ((const float4*)src)[2*i + 1];
    s16x8 pk;
    pk[0] = (short)f2bf(v0.x); pk[1] = (short)f2bf(v0.y);
    pk[2] = (short)f2bf(v0.z); pk[3] = (short)f2bf(v0.w);
    pk[4] = (short)f2bf(v1.x); pk[5] = (short)f2bf(v1.y);
    pk[6] = (short)f2bf(v1.z); pk[7] = (short)f2bf(v1.w);
    *(s16x8*)&dst[i*8] = pk;
  } else {
    int i0 = ((blk - 3648)*256 + tid)*4;     // 65536 total
    #pragma unroll
    for (int j = 0; j < 4; j++) {
      int i = i0 + j;
      int h = i >> 12, rc = i & 4095;
      bias[i] = table[rel_idx[rc] * 16 + h];
    }
  }
}

// ================= shared 4-phase counted-vmcnt loop (r12 config, HW-validated):
// 256x256 tile, 8 waves (2x4), BK=64, 8 K-tiles, 2 load-bearing barriers/tile.
struct GemmCtx {
  ushort_t* lds;
  const ushort_t *pA0, *pA1, *pB0, *pB1;
  int w, lane, wm, wn;
};

template<int BUFP, int KH, int RH, int SSEL, int SBUFP, int SU, int VM, bool BAR>
__device__ __forceinline__ void phase(const GemmCtx& C, f32x4 (&acc)[8][4], s16x8 (&bf)[4], int stau) {
  s16x8 af[4];
  #pragma unroll
  for (int t = 0; t < 4; t++)
    af[t] = *(const s16x8*)&C.lds[BUFP*32768 + ((C.wm*8 + RH*4 + t)*2 + KH)*512 + C.lane*8];
  if constexpr (RH == 0) {
    #pragma unroll
    for (int t = 0; t < 4; t++)
      bf[t] = *(const s16x8*)&C.lds[BUFP*32768 + 16384 + ((C.wn*4 + t)*2 + KH)*512 + C.lane*8];
  }
  if constexpr (SSEL == 0) {
    gl_lds16(C.pA0 + stau*64 + SU*32, C.lds + SBUFP*32768 + (4*C.w + SU)*512);
    gl_lds16(C.pA1 + stau*64 + SU*32, C.lds + SBUFP*32768 + (4*C.w + 2 + SU)*512);
  } else if constexpr (SSEL == 1) {
    gl_lds16(C.pB0 + stau*64 + SU*32, C.lds + SBUFP*32768 + 16384 + (4*C.w + SU)*512);
    gl_lds16(C.pB1 + stau*64 + SU*32, C.lds + SBUFP*32768 + 16384 + (4*C.w + 2 + SU)*512);
  }
  if constexpr (VM == 8) asm volatile("s_waitcnt vmcnt(8)" ::: "memory");
  else if constexpr (VM == 4) asm volatile("s_waitcnt vmcnt(4)" ::: "memory");
  else if constexpr (VM == 0) asm volatile("s_waitcnt vmcnt(0)" ::: "memory");
  __builtin_amdgcn_s_setprio(1);
  #pragma unroll
  for (int ta = 0; ta < 4; ta++)
    #pragma unroll
    for (int tb = 0; tb < 4; tb++)
      acc[RH*4 + ta][tb] = __builtin_amdgcn_mfma_f32_16x16x32_bf16(af[ta], bf[tb], acc[RH*4 + ta][tb], 0, 0, 0);
  __builtin_amdgcn_s_setprio(0);
  if constexpr (BAR) __builtin_amdgcn_s_barrier();
}

// per K-tile tau: q1 stages A-kh1(tau+1), q2 B-kh1(tau+1) [vmcnt, BARRIER],
//                 q3 stages A-kh0(tau+2), q4 B-kh0(tau+2) [vmcnt, BARRIER]
template<int BUFP, bool S12, bool S34, int VM2, int VM4>
__device__ __forceinline__ void ktile(const GemmCtx& C, f32x4 (&acc)[8][4], int tau) {
  s16x8 bf[4];
  phase<BUFP, 0, 0, S12 ? 0 : -1, BUFP^1, 1, -1,  false>(C, acc, bf, tau + 1);
  phase<BUFP, 0, 1, S12 ? 1 : -1, BUFP^1, 1, VM2, true >(C, acc, bf, tau + 1);
  phase<BUFP, 1, 0, S34 ? 0 : -1, BUFP,   0, -1,  false>(C, acc, bf, tau + 2);
  phase<BUFP, 1, 1, S34 ? 1 : -1, BUFP,   0, VM4, true >(C, acc, bf, tau + 2);
}

// prologue + full K-loop, shared by QKV and proj
__device__ __forceinline__ void run_gemm_loop(const GemmCtx& C, f32x4 (&acc)[8][4]) {
  ushort_t* lds = C.lds;
  const int w = C.w;
  gl_lds16(C.pA0 +  0, lds + (4*w + 0)*512);
  gl_lds16(C.pA1 +  0, lds + (4*w + 2)*512);
  gl_lds16(C.pB0 +  0, lds + 16384 + (4*w + 0)*512);
  gl_lds16(C.pB1 +  0, lds + 16384 + (4*w + 2)*512);
  gl_lds16(C.pA0 + 32, lds + (4*w + 1)*512);
  gl_lds16(C.pA1 + 32, lds + (4*w + 3)*512);
  gl_lds16(C.pB0 + 32, lds + 16384 + (4*w + 1)*512);
  gl_lds16(C.pB1 + 32, lds + 16384 + (4*w + 3)*512);
  gl_lds16(C.pA0 + 64, lds + 32768 + (4*w + 0)*512);
  gl_lds16(C.pA1 + 64, lds + 32768 + (4*w + 2)*512);
  gl_lds16(C.pB0 + 64, lds + 32768 + 16384 + (4*w + 0)*512);
  gl_lds16(C.pB1 + 64, lds + 32768 + 16384 + (4*w + 2)*512);
  asm volatile("s_waitcnt vmcnt(4)" ::: "memory");
  __builtin_amdgcn_s_barrier();

  for (int kt = 0; kt < 6; kt += 2) {
    ktile<0, true, true, 8, 8>(C, acc, kt);
    ktile<1, true, true, 8, 8>(C, acc, kt + 1);
  }
  ktile<0, true,  false, 8, 4>(C, acc, 6);   // tail: vmcnt(4) guards tile7 kh0
  ktile<1, false, false, 0, -1>(C, acc, 7);  // tail: vmcnt(0) guards tile7 kh1
}

// ================= QKV GEMM (r12 config; best-measured 242 µs).
__global__ __launch_bounds__(512, 2) void k_gemm_qkv(
    const ushort_t* __restrict__ xh, const ushort_t* __restrict__ wh,
    ushort_t* __restrict__ qh, ushort_t* __restrict__ kh, ushort_t* __restrict__ vt) {
  extern __shared__ __align__(16) ushort_t lds[];
  const int tid = threadIdx.x, w = tid >> 6, lane = tid & 63;
  const int g = lane >> 4, l15 = lane & 15;
  const int wm = w >> 2, wn = w & 3;
  int flat = blockIdx.x;                 // 2352 = 8*294, bijective XCD swizzle
  int swz = (flat & 7) * 294 + (flat >> 3);
  int bx = swz % 6, by = swz / 6;        // bx fastest -> A-panel L2 reuse per XCD

  GemmCtx C;
  C.lds = lds;
  C.pA0 = xh + ((size_t)by*256 + (size_t)(2*w)*16 + l15)*512 + g*8;
  C.pA1 = C.pA0 + 16*512;
  C.pB0 = wh + ((size_t)bx*256 + (size_t)(2*w)*16 + l15)*512 + g*8;
  C.pB1 = C.pB0 + 16*512;
  C.w = w; C.lane = lane; C.wm = wm; C.wn = wn;

  f32x4 acc[8][4];
  #pragma unroll
  for (int r = 0; r < 8; r++)
    #pragma unroll
    for (int c = 0; c < 4; c++) acc[r][c] = (f32x4){0.f, 0.f, 0.f, 0.f};

  run_gemm_loop(C, acc);

  // ---- epilogue: acc -> LDS (swizzled, conflict-free), coalesced stores.
  // 32 regions (b_i*8+h_i) x 2048 elems = 128 KiB. bx: 0,1->q  2,3->k  4,5->v(T)
  asm volatile("" ::: "memory");
  const int sel = bx >> 1;
  if (sel < 2) {
    #pragma unroll
    for (int ra = 0; ra < 8; ra++)
      #pragma unroll
      for (int tb = 0; tb < 4; tb++)
        #pragma unroll
        for (int j = 0; j < 4; j++) {
          int row = wm*128 + ra*16 + g*4 + j;
          int col = wn*64 + tb*16 + l15;
          int r = (row >> 6)*8 + (col >> 5);
          int n = row & 63, d = col & 31;
          int byte = r*4096 + ((n*64 + d*2) ^ ((n & 12) << 3));
          *(ushort_t*)((char*)lds + byte) = f2bf(acc[ra][tb][j]);
        }
  } else {
    #pragma unroll
    for (int ra = 0; ra < 8; ra++)
      #pragma unroll
      for (int tb = 0; tb < 4; tb++) {
        int row0 = wm*128 + ra*16 + g*4;
        int col = wn*64 + tb*16 + l15;
        int r = (row0 >> 6)*8 + (col >> 5);
        int n0 = row0 & 63, d = col & 31;
        u64_t pk = (u64_t)f2bf(acc[ra][tb][0])
                 | ((u64_t)f2bf(acc[ra][tb][1]) << 16)
                 | ((u64_t)f2bf(acc[ra][tb][2]) << 32)
                 | ((u64_t)f2bf(acc[ra][tb][3]) << 48);
        int byte = r*4096 + ((d*128 + n0*2) ^ ((d & 7) << 4) ^ (((((d >> 3) ^ (n0 >> 3))) & 1) << 6));
        *(u64_t*)((char*)lds + byte) = pk;
      }
  }
  asm volatile("s_waitcnt lgkmcnt(0)" ::: "memory");
  __builtin_amdgcn_s_barrier();
  ushort_t* dst = (sel == 0) ? qh : (sel == 1) ? kh : vt;
  const int hbase = (bx & 1) * 8;
  #pragma unroll
  for (int it = 0; it < 16; it++) {
    int cg = it*512 + tid;
    int r = cg >> 8, inner = cg & 255;
    int byte;
    if (sel < 2) byte = r*4096 + ((inner*16) ^ (((inner >> 2) & 12) << 3));
    else         byte = r*4096 + ((inner*16) ^ (((inner >> 3) & 7) << 4) ^ ((((inner >> 6) ^ inner) & 1) << 6));
    s16x8 v = *(const s16x8*)((const char*)lds + byte);
    int b = by*4 + (r >> 3), h = hbase + (r & 7);
    *(s16x8*)&dst[(size_t)(b*16 + h)*2048 + inner*8] = v;
  }
}

// ================= proj GEMM: NEW — same 4-phase counted-vmcnt loop as QKV,
// r11's proven f32 2-pass swizzled epilogue. K-order identical -> bit-identical.
__global__ __launch_bounds__(512, 2) void k_gemm_proj(
    const ushort_t* __restrict__ ah, const ushort_t* __restrict__ wh,
    const float* __restrict__ pb, float* __restrict__ out) {
  extern __shared__ __align__(16) ushort_t lds[];
  const int tid = threadIdx.x, w = tid >> 6, lane = tid & 63;
  const int g = lane >> 4, l15 = lane & 15;
  const int wm = w >> 2, wn = w & 3;
  int flat = blockIdx.x;                 // 784 = 8*98, bijective XCD swizzle
  int swz = (flat & 7) * 98 + (flat >> 3);
  int bx = swz & 1, by = swz >> 1;

  GemmCtx C;
  C.lds = lds;
  C.pA0 = ah + ((size_t)by*256 + (size_t)(2*w)*16 + l15)*512 + g*8;
  C.pA1 = C.pA0 + 16*512;
  C.pB0 = wh + ((size_t)bx*256 + (size_t)(2*w)*16 + l15)*512 + g*8;
  C.pB1 = C.pB0 + 16*512;
  C.w = w; C.lane = lane; C.wm = wm; C.wn = wn;

  f32x4 acc[8][4];
  #pragma unroll
  for (int r = 0; r < 8; r++)
    #pragma unroll
    for (int c = 0; c < 4; c++) acc[r][c] = (f32x4){0.f, 0.f, 0.f, 0.f};

  run_gemm_loop(C, acc);

  // ---- epilogue: two passes of 128 rows x 256 cols f32 (128 KiB), swizzled.
  asm volatile("" ::: "memory");
  #pragma unroll
  for (int p = 0; p < 2; p++) {
    if (p) { asm volatile("" ::: "memory"); __builtin_amdgcn_s_barrier(); }
    if (wm == p) {
      #pragma unroll
      for (int ra = 0; ra < 8; ra++)
        #pragma unroll
        for (int tb = 0; tb < 4; tb++)
          #pragma unroll
          for (int j = 0; j < 4; j++) {
            int row = ra*16 + g*4 + j;          // local 0-127
            int col = wn*64 + tb*16 + l15;
            int byte = (row*1024 + col*4) ^ ((row & 12) << 2) ^ ((row & 8) << 3);
            *(float*)((char*)lds + byte) = acc[ra][tb][j];
          }
    }
    asm volatile("s_waitcnt lgkmcnt(0)" ::: "memory");
    __builtin_amdgcn_s_barrier();
    #pragma unroll
    for (int it = 0; it < 16; it++) {
      int cg = it*512 + tid;
      int row = cg >> 6, c16 = cg & 63;
      int byte = row*1024 + ((c16*16) ^ ((row & 12) << 2) ^ ((row & 8) << 3));
      f32x4 v = *(const f32x4*)((const char*)lds + byte);
      int ncol = bx*256 + c16*4;
      f32x4 pbv = *(const f32x4*)&pb[ncol];
      v = v + pbv;
      *(f32x4*)&out[(size_t)(by*256 + p*128 + row)*512 + ncol] = v;
    }
  }
}

// ---------- kernel 3: attention (r15 config: fragment-linear P, 3 blocks/CU).
__global__ __launch_bounds__(256) void k_attn(
    const ushort_t* __restrict__ qh, const ushort_t* __restrict__ kh,
    const ushort_t* __restrict__ vt, const float* __restrict__ bias,
    ushort_t* __restrict__ aoh) {
  __shared__ ushort_t plds[4][4096];       // fragment-linear P, per wave
  __shared__ float blds[64*68];            // pitch 68 -> only free 2-way conflicts
  const int tid = threadIdx.x, w = tid >> 6, lane = tid & 63;
  const int g = lane >> 4, l15 = lane & 15;
  const int h = blockIdx.x & 15;
  const int b = (blockIdx.x >> 4)*4 + w;   // 392 b-groups x 16 heads
  const size_t base = (size_t)(b*16 + h) * 2048;

  s16x8 qf[4], kf[4];
  #pragma unroll
  for (int t = 0; t < 4; t++) {
    size_t o = base + (size_t)(t*16 + l15)*32 + g*8;
    qf[t] = *(const s16x8*)&qh[o];
    kf[t] = *(const s16x8*)&kh[o];
  }
  s16x8 vf[2][2];
  #pragma unroll
  for (int kt = 0; kt < 2; kt++)
    #pragma unroll
    for (int nt = 0; nt < 2; nt++)
      vf[kt][nt] = *(const s16x8*)&vt[base + (size_t)(nt*16 + l15)*64 + kt*32 + g*8];

  const float* bh_ = bias + ((size_t)h << 12);
  #pragma unroll
  for (int it = 0; it < 4; it++) {
    int idx = it*1024 + tid*4;
    int rr = idx >> 6, cc = idx & 63;
    *(f32x4*)&blds[rr*68 + cc] = *(const f32x4*)&bh_[idx];
  }
  __syncthreads();

  f32x4 s[4][4];
  #pragma unroll
  for (int r = 0; r < 4; r++)
    #pragma unroll
    for (int c = 0; c < 4; c++) s[r][c] = (f32x4){0.f,0.f,0.f,0.f};
  #pragma unroll
  for (int r = 0; r < 4; r++)
    #pragma unroll
    for (int c = 0; c < 4; c++)
      s[r][c] = __builtin_amdgcn_mfma_f32_16x16x32_bf16(qf[r], kf[c], s[r][c], 0, 0, 0);

  const float invs = 0.17677669529663687f;  // 1/sqrt(32)
  #pragma unroll
  for (int r = 0; r < 4; r++)
    #pragma unroll
    for (int c = 0; c < 4; c++)
      #pragma unroll
      for (int j = 0; j < 4; j++) {
        int rr = r*16 + g*4 + j, cc = c*16 + l15;
        s[r][c][j] = s[r][c][j]*invs + blds[rr*68 + cc];
      }

  #pragma unroll
  for (int r = 0; r < 4; r++)
    #pragma unroll
    for (int j = 0; j < 4; j++) {
      float mx = fmaxf(fmaxf(s[r][0][j], s[r][1][j]), fmaxf(s[r][2][j], s[r][3][j]));
      mx = fmaxf(mx, __shfl_xor(mx, 1));
      mx = fmaxf(mx, __shfl_xor(mx, 2));
      mx = fmaxf(mx, __shfl_xor(mx, 4));
      mx = fmaxf(mx, __shfl_xor(mx, 8));
      float p0 = __expf(s[r][0][j]-mx), p1 = __expf(s[r][1][j]-mx);
      float p2 = __expf(s[r][2][j]-mx), p3 = __expf(s[r][3][j]-mx);
      float sum = p0 + p1 + p2 + p3;
      sum += __shfl_xor(sum, 1);
      sum += __shfl_xor(sum, 2);
      sum += __shfl_xor(sum, 4);
      sum += __shfl_xor(sum, 8);
      float rv = 1.0f / sum;
      s[r][0][j] = p0*rv; s[r][1][j] = p1*rv; s[r][2][j] = p2*rv; s[r][3][j] = p3*rv;
    }

  ushort_t* Pw = plds[w];
  asm volatile("s_waitcnt lgkmcnt(0)" ::: "memory");
  __builtin_amdgcn_sched_barrier(0);
  #pragma unroll
  for (int r = 0; r < 4; r++)
    #pragma unroll
    for (int c = 0; c < 4; c++)
      #pragma unroll
      for (int j = 0; j < 4; j++) {
        int idx = ((c >> 1)*4 + r)*512 + ((((c & 1)*2) + (l15 >> 3))*16 + g*4 + j)*8 + (l15 & 7);
        Pw[idx] = f2bf(s[r][c][j]);
      }
  asm volatile("s_waitcnt lgkmcnt(0)" ::: "memory");
  __builtin_amdgcn_sched_barrier(0);

  s16x8 pf[4][2];
  #pragma unroll
  for (int ta = 0; ta < 4; ta++)
    #pragma unroll
    for (int kt = 0; kt < 2; kt++)
      pf[ta][kt] = *(const s16x8*)&Pw[(kt*4 + ta)*512 + lane*8];

  f32x4 o[4][2];
  #pragma unroll
  for (int ta = 0; ta < 4; ta++)
    #pragma unroll
    for (int nt = 0; nt < 2; nt++) o[ta][nt] = (f32x4){0.f,0.f,0.f,0.f};
  #pragma unroll
  for (int ta = 0; ta < 4; ta++)
    #pragma unroll
    for (int nt = 0; nt < 2; nt++)
      #pragma unroll
      for (int kt = 0; kt < 2; kt++)
        o[ta][nt] = __builtin_amdgcn_mfma_f32_16x16x32_bf16(pf[ta][kt], vf[kt][nt], o[ta][nt], 0, 0, 0);

  #pragma unroll
  for (int ta = 0; ta < 4; ta++)
    #pragma unroll
    for (int nt = 0; nt < 2; nt++)
      #pragma unroll
      for (int j = 0; j < 4; j++) {
        int rr = ta*16 + g*4 + j, dd = nt*16 + l15;
        aoh[((size_t)b*64 + rr)*512 + h*32 + dd] = f2bf(o[ta][nt][j]);
      }
}

extern "C" void kernel_launch(void* const* d_in, const int* in_sizes, int n_in,
                              void* d_out, int out_size, void* d_ws, size_t ws_size,
                              hipStream_t stream) {
  const float* x      = (const float*)d_in[0];
  const float* qkv_w  = (const float*)d_in[1];
  const float* table  = (const float*)d_in[2];
  const float* proj_w = (const float*)d_in[3];
  const float* proj_b = (const float*)d_in[4];
  const int*   rel_idx = (const int*)d_in[5];

  const size_t S1 = S1_ELEMS;
  const size_t need = (4*S1 + 786432 + 262144)*sizeof(ushort_t) + 65536*sizeof(float);
  if (ws_size < need) return;

  ushort_t* qh  = (ushort_t*)d_ws;
  ushort_t* kh  = qh + S1;
  ushort_t* vt  = kh + S1;
  ushort_t* xh  = vt + S1;        // reused as attention-out after QKV GEMM
  ushort_t* wqh = xh + S1;
  ushort_t* wph = wqh + 786432;
  float*    bias = (float*)(wph + 262144);
  ushort_t* aoh = xh;

  hipFuncSetAttribute((const void*)k_gemm_qkv,
                      hipFuncAttributeMaxDynamicSharedMemorySize, 131072);
  hipFuncSetAttribute((const void*)k_gemm_proj,
                      hipFuncAttributeMaxDynamicSharedMemorySize, 131072);

  k_prep<<<3712, 256, 0, stream>>>(x, xh, qkv_w, wqh, proj_w, wph, table, rel_idx, bias);
  k_gemm_qkv<<<2352, 512, 131072, stream>>>(xh, wqh, qh, kh, vt);
  k_attn<<<6272, 256, 0, stream>>>(qh, kh, vt, bias, aoh);
  k_gemm_proj<<<784, 512, 131072, stream>>>(aoh, wph, proj_b, (float*)d_out);
}

// Round 18
// 507.094 us; speedup vs baseline: 1.0479x; 1.0019x over previous
//
#include <hip/hip_runtime.h>
#include <stdint.h>

typedef unsigned short ushort_t;
typedef unsigned long long u64_t;
typedef __attribute__((ext_vector_type(4))) float f32x4;
typedef __attribute__((ext_vector_type(8))) short s16x8;

#define S1_ELEMS ((size_t)1568*64*512)   // 51,380,224 elements per q/k/v/x buffer

// ---------- bf16 helpers (RNE)
__device__ __forceinline__ ushort_t f2bf(float f) {
  unsigned u = __builtin_bit_cast(unsigned, f);
  u = u + 0x7fffu + ((u >> 16) & 1u);
  return (ushort_t)(u >> 16);
}

// ---------- async global->LDS, 16B per lane (dest = uniform base + lane*16)
__device__ __forceinline__ void gl_lds16(const ushort_t* g, ushort_t* l) {
  typedef __attribute__((address_space(1))) void gvoid;
  typedef __attribute__((address_space(3))) void lvoid;
  __builtin_amdgcn_global_load_lds((gvoid*)(ushort_t*)g, (lvoid*)l, 16, 0, 0);
}

// ---------- kernel 1: merged prep — x/wq/wp f32->bf16 convert + bias gather.
__global__ void k_prep(const float* __restrict__ x, ushort_t* __restrict__ xh,
                       const float* __restrict__ wq, ushort_t* __restrict__ wqh,
                       const float* __restrict__ wp, ushort_t* __restrict__ wph,
                       const float* __restrict__ table, const int* __restrict__ rel_idx,
                       float* __restrict__ bias) {
  int blk = blockIdx.x, tid = threadIdx.x;
  if (blk < 3136) {
    long i0 = (long)blk*256 + tid;
    #pragma unroll
    for (int rep = 0; rep < 8; rep++) {
      long i = i0 + (long)rep*802816;
      float4 v0 = ((const float4*)x)[2*i];
      float4 v1 = ((const float4*)x)[2*i + 1];
      s16x8 pk;
      pk[0] = (short)f2bf(v0.x); pk[1] = (short)f2bf(v0.y);
      pk[2] = (short)f2bf(v0.z); pk[3] = (short)f2bf(v0.w);
      pk[4] = (short)f2bf(v1.x); pk[5] = (short)f2bf(v1.y);
      pk[6] = (short)f2bf(v1.z); pk[7] = (short)f2bf(v1.w);
      *(s16x8*)&xh[i*8] = pk;
    }
  } else if (blk < 3648) {
    const float* src; ushort_t* dst; long i;
    if (blk < 3520) { src = wq; dst = wqh; i = (long)(blk - 3136)*256 + tid; }
    else            { src = wp; dst = wph; i = (long)(blk - 3520)*256 + tid; }
    float4 v0 = ((const float4*)src)[2*i];
    float4 v1 = ((const float4*)src)[2*i + 1];
    s16x8 pk;
    pk[0] = (short)f2bf(v0.x); pk[1] = (short)f2bf(v0.y);
    pk[2] = (short)f2bf(v0.z); pk[3] = (short)f2bf(v0.w);
    pk[4] = (short)f2bf(v1.x); pk[5] = (short)f2bf(v1.y);
    pk[6] = (short)f2bf(v1.z); pk[7] = (short)f2bf(v1.w);
    *(s16x8*)&dst[i*8] = pk;
  } else {
    int i0 = ((blk - 3648)*256 + tid)*4;     // 65536 total
    #pragma unroll
    for (int j = 0; j < 4; j++) {
      int i = i0 + j;
      int h = i >> 12, rc = i & 4095;
      bias[i] = table[rel_idx[rc] * 16 + h];
    }
  }
}

// ================= shared 4-phase counted-vmcnt loop (r12 config, HW-validated):
// 256x256 tile, 8 waves (2x4), BK=64, 8 K-tiles, 2 load-bearing barriers/tile.
struct GemmCtx {
  ushort_t* lds;
  const ushort_t *pA0, *pA1, *pB0, *pB1;
  int w, lane, wm, wn;
};

template<int BUFP, int KH, int RH, int SSEL, int SBUFP, int SU, int VM, bool BAR>
__device__ __forceinline__ void phase(const GemmCtx& C, f32x4 (&acc)[8][4], s16x8 (&bf)[4], int stau) {
  s16x8 af[4];
  #pragma unroll
  for (int t = 0; t < 4; t++)
    af[t] = *(const s16x8*)&C.lds[BUFP*32768 + ((C.wm*8 + RH*4 + t)*2 + KH)*512 + C.lane*8];
  if constexpr (RH == 0) {
    #pragma unroll
    for (int t = 0; t < 4; t++)
      bf[t] = *(const s16x8*)&C.lds[BUFP*32768 + 16384 + ((C.wn*4 + t)*2 + KH)*512 + C.lane*8];
  }
  if constexpr (SSEL == 0) {
    gl_lds16(C.pA0 + stau*64 + SU*32, C.lds + SBUFP*32768 + (4*C.w + SU)*512);
    gl_lds16(C.pA1 + stau*64 + SU*32, C.lds + SBUFP*32768 + (4*C.w + 2 + SU)*512);
  } else if constexpr (SSEL == 1) {
    gl_lds16(C.pB0 + stau*64 + SU*32, C.lds + SBUFP*32768 + 16384 + (4*C.w + SU)*512);
    gl_lds16(C.pB1 + stau*64 + SU*32, C.lds + SBUFP*32768 + 16384 + (4*C.w + 2 + SU)*512);
  }
  if constexpr (VM == 8) asm volatile("s_waitcnt vmcnt(8)" ::: "memory");
  else if constexpr (VM == 4) asm volatile("s_waitcnt vmcnt(4)" ::: "memory");
  else if constexpr (VM == 0) asm volatile("s_waitcnt vmcnt(0)" ::: "memory");
  __builtin_amdgcn_s_setprio(1);
  #pragma unroll
  for (int ta = 0; ta < 4; ta++)
    #pragma unroll
    for (int tb = 0; tb < 4; tb++)
      acc[RH*4 + ta][tb] = __builtin_amdgcn_mfma_f32_16x16x32_bf16(af[ta], bf[tb], acc[RH*4 + ta][tb], 0, 0, 0);
  __builtin_amdgcn_s_setprio(0);
  if constexpr (BAR) __builtin_amdgcn_s_barrier();
}

template<int BUFP, bool S12, bool S34, int VM2, int VM4>
__device__ __forceinline__ void ktile(const GemmCtx& C, f32x4 (&acc)[8][4], int tau) {
  s16x8 bf[4];
  phase<BUFP, 0, 0, S12 ? 0 : -1, BUFP^1, 1, -1,  false>(C, acc, bf, tau + 1);
  phase<BUFP, 0, 1, S12 ? 1 : -1, BUFP^1, 1, VM2, true >(C, acc, bf, tau + 1);
  phase<BUFP, 1, 0, S34 ? 0 : -1, BUFP,   0, -1,  false>(C, acc, bf, tau + 2);
  phase<BUFP, 1, 1, S34 ? 1 : -1, BUFP,   0, VM4, true >(C, acc, bf, tau + 2);
}

__device__ __forceinline__ void run_gemm_loop(const GemmCtx& C, f32x4 (&acc)[8][4]) {
  ushort_t* lds = C.lds;
  const int w = C.w;
  gl_lds16(C.pA0 +  0, lds + (4*w + 0)*512);
  gl_lds16(C.pA1 +  0, lds + (4*w + 2)*512);
  gl_lds16(C.pB0 +  0, lds + 16384 + (4*w + 0)*512);
  gl_lds16(C.pB1 +  0, lds + 16384 + (4*w + 2)*512);
  gl_lds16(C.pA0 + 32, lds + (4*w + 1)*512);
  gl_lds16(C.pA1 + 32, lds + (4*w + 3)*512);
  gl_lds16(C.pB0 + 32, lds + 16384 + (4*w + 1)*512);
  gl_lds16(C.pB1 + 32, lds + 16384 + (4*w + 3)*512);
  gl_lds16(C.pA0 + 64, lds + 32768 + (4*w + 0)*512);
  gl_lds16(C.pA1 + 64, lds + 32768 + (4*w + 2)*512);
  gl_lds16(C.pB0 + 64, lds + 32768 + 16384 + (4*w + 0)*512);
  gl_lds16(C.pB1 + 64, lds + 32768 + 16384 + (4*w + 2)*512);
  asm volatile("s_waitcnt vmcnt(4)" ::: "memory");
  __builtin_amdgcn_s_barrier();

  for (int kt = 0; kt < 6; kt += 2) {
    ktile<0, true, true, 8, 8>(C, acc, kt);
    ktile<1, true, true, 8, 8>(C, acc, kt + 1);
  }
  ktile<0, true,  false, 8, 4>(C, acc, 6);   // tail: vmcnt(4) guards tile7 kh0
  ktile<1, false, false, 0, -1>(C, acc, 7);  // tail: vmcnt(0) guards tile7 kh1
}

// ================= QKV GEMM (r12 config; best-measured 242 µs).
__global__ __launch_bounds__(512, 2) void k_gemm_qkv(
    const ushort_t* __restrict__ xh, const ushort_t* __restrict__ wh,
    ushort_t* __restrict__ qh, ushort_t* __restrict__ kh, ushort_t* __restrict__ vt) {
  extern __shared__ __align__(16) ushort_t lds[];
  const int tid = threadIdx.x, w = tid >> 6, lane = tid & 63;
  const int g = lane >> 4, l15 = lane & 15;
  const int wm = w >> 2, wn = w & 3;
  int flat = blockIdx.x;                 // 2352 = 8*294, bijective XCD swizzle
  int swz = (flat & 7) * 294 + (flat >> 3);
  int bx = swz % 6, by = swz / 6;        // bx fastest -> A-panel L2 reuse per XCD

  GemmCtx C;
  C.lds = lds;
  C.pA0 = xh + ((size_t)by*256 + (size_t)(2*w)*16 + l15)*512 + g*8;
  C.pA1 = C.pA0 + 16*512;
  C.pB0 = wh + ((size_t)bx*256 + (size_t)(2*w)*16 + l15)*512 + g*8;
  C.pB1 = C.pB0 + 16*512;
  C.w = w; C.lane = lane; C.wm = wm; C.wn = wn;

  f32x4 acc[8][4];
  #pragma unroll
  for (int r = 0; r < 8; r++)
    #pragma unroll
    for (int c = 0; c < 4; c++) acc[r][c] = (f32x4){0.f, 0.f, 0.f, 0.f};

  run_gemm_loop(C, acc);

  // ---- epilogue: acc -> LDS (swizzled, conflict-free), coalesced stores.
  asm volatile("" ::: "memory");
  const int sel = bx >> 1;
  if (sel < 2) {
    #pragma unroll
    for (int ra = 0; ra < 8; ra++)
      #pragma unroll
      for (int tb = 0; tb < 4; tb++)
        #pragma unroll
        for (int j = 0; j < 4; j++) {
          int row = wm*128 + ra*16 + g*4 + j;
          int col = wn*64 + tb*16 + l15;
          int r = (row >> 6)*8 + (col >> 5);
          int n = row & 63, d = col & 31;
          int byte = r*4096 + ((n*64 + d*2) ^ ((n & 12) << 3));
          *(ushort_t*)((char*)lds + byte) = f2bf(acc[ra][tb][j]);
        }
  } else {
    #pragma unroll
    for (int ra = 0; ra < 8; ra++)
      #pragma unroll
      for (int tb = 0; tb < 4; tb++) {
        int row0 = wm*128 + ra*16 + g*4;
        int col = wn*64 + tb*16 + l15;
        int r = (row0 >> 6)*8 + (col >> 5);
        int n0 = row0 & 63, d = col & 31;
        u64_t pk = (u64_t)f2bf(acc[ra][tb][0])
                 | ((u64_t)f2bf(acc[ra][tb][1]) << 16)
                 | ((u64_t)f2bf(acc[ra][tb][2]) << 32)
                 | ((u64_t)f2bf(acc[ra][tb][3]) << 48);
        int byte = r*4096 + ((d*128 + n0*2) ^ ((d & 7) << 4) ^ (((((d >> 3) ^ (n0 >> 3))) & 1) << 6));
        *(u64_t*)((char*)lds + byte) = pk;
      }
  }
  asm volatile("s_waitcnt lgkmcnt(0)" ::: "memory");
  __builtin_amdgcn_s_barrier();
  ushort_t* dst = (sel == 0) ? qh : (sel == 1) ? kh : vt;
  const int hbase = (bx & 1) * 8;
  #pragma unroll
  for (int it = 0; it < 16; it++) {
    int cg = it*512 + tid;
    int r = cg >> 8, inner = cg & 255;
    int byte;
    if (sel < 2) byte = r*4096 + ((inner*16) ^ (((inner >> 2) & 12) << 3));
    else         byte = r*4096 + ((inner*16) ^ (((inner >> 3) & 7) << 4) ^ ((((inner >> 6) ^ inner) & 1) << 6));
    s16x8 v = *(const s16x8*)((const char*)lds + byte);
    int b = by*4 + (r >> 3), h = hbase + (r & 7);
    *(s16x8*)&dst[(size_t)(b*16 + h)*2048 + inner*8] = v;
  }
}

// ================= proj GEMM: 128x256 tile, BK=32, 16 K-tiles, 8 waves (2x4),
// acc[4][4]=64 VGPR + 72 KiB LDS -> 2 blocks/CU (r16-verified mechanics; B panel
// is 0.5 MB and L2-resident, so this shape's extra B staging is L2-fed, unlike
// the QKV case where it regressed). Triple-buffered 24 KiB stages, depth-2
// counted vmcnt(3), one barrier/tile. K-order t*32 sequential -> bit-identical.
__global__ __launch_bounds__(512, 4) void k_gemm_proj(
    const ushort_t* __restrict__ ah, const ushort_t* __restrict__ wh,
    const float* __restrict__ pb, float* __restrict__ out) {
  extern __shared__ __align__(16) ushort_t lds[];   // 3 bufs x 12288 ushort
  const int tid = threadIdx.x, w = tid >> 6, lane = tid & 63;
  const int g = lane >> 4, l15 = lane & 15;
  const int wm = w >> 2, wn = w & 3;
  int flat = blockIdx.x;                 // 1568 = 8*196, bijective XCD swizzle
  int swz = (flat & 7) * 196 + (flat >> 3);
  int bx = swz & 1, by = swz >> 1;

  // wave w stages: A subtile w (1 KiB), B subtiles 2w, 2w+1
  const ushort_t* pA  = ah + ((size_t)(by*128 + w*16 + l15))*512 + g*8;
  const ushort_t* pB0 = wh + ((size_t)(bx*256 + (2*w)*16 + l15))*512 + g*8;
  const ushort_t* pB1 = pB0 + 16*512;

  f32x4 acc[4][4];
  #pragma unroll
  for (int r = 0; r < 4; r++)
    #pragma unroll
    for (int c = 0; c < 4; c++) acc[r][c] = (f32x4){0.f, 0.f, 0.f, 0.f};

  // prologue: tiles 0,1 into bufs 0,1 (3 issues/wave each)
  #pragma unroll
  for (int t0 = 0; t0 < 2; t0++) {
    ushort_t* buf = lds + t0*12288;
    gl_lds16(pA  + t0*32, buf + w*512);
    gl_lds16(pB0 + t0*32, buf + 4096 + (2*w)*512);
    gl_lds16(pB1 + t0*32, buf + 4096 + (2*w + 1)*512);
  }

  #pragma unroll
  for (int t = 0; t < 16; ++t) {
    if (t == 15) asm volatile("s_waitcnt vmcnt(0)" ::: "memory");
    else         asm volatile("s_waitcnt vmcnt(3)" ::: "memory");
    __builtin_amdgcn_s_barrier();
    if (t < 14) {                        // stage tile t+2 (issued post-barrier)
      ushort_t* bufS = lds + ((t + 2) % 3)*12288;
      gl_lds16(pA  + (t + 2)*32, bufS + w*512);
      gl_lds16(pB0 + (t + 2)*32, bufS + 4096 + (2*w)*512);
      gl_lds16(pB1 + (t + 2)*32, bufS + 4096 + (2*w + 1)*512);
    }
    ushort_t* buf = lds + (t % 3)*12288;
    s16x8 af[4], bf[4];
    #pragma unroll
    for (int ta = 0; ta < 4; ta++)
      af[ta] = *(const s16x8*)&buf[(wm*4 + ta)*512 + lane*8];
    #pragma unroll
    for (int tb = 0; tb < 4; tb++)
      bf[tb] = *(const s16x8*)&buf[4096 + (wn*4 + tb)*512 + lane*8];
    __builtin_amdgcn_s_setprio(1);
    #pragma unroll
    for (int ta = 0; ta < 4; ta++)
      #pragma unroll
      for (int tb = 0; tb < 4; tb++)
        acc[ta][tb] = __builtin_amdgcn_mfma_f32_16x16x32_bf16(af[ta], bf[tb], acc[ta][tb], 0, 0, 0);
    __builtin_amdgcn_s_setprio(0);
  }

  // ---- epilogue: direct f32 stores + bias (r13-proven 64B-segment pattern).
  float pbv[4];
  #pragma unroll
  for (int tb = 0; tb < 4; tb++) pbv[tb] = pb[bx*256 + wn*64 + tb*16 + l15];
  #pragma unroll
  for (int ta = 0; ta < 4; ta++)
    #pragma unroll
    for (int tb = 0; tb < 4; tb++)
      #pragma unroll
      for (int j = 0; j < 4; j++) {
        int row = by*128 + wm*64 + ta*16 + g*4 + j;
        int col = bx*256 + wn*64 + tb*16 + l15;
        out[(size_t)row*512 + col] = acc[ta][tb][j] + pbv[tb];
      }
}

// ---------- kernel 3: attention (r15 config: fragment-linear P, 3 blocks/CU).
__global__ __launch_bounds__(256) void k_attn(
    const ushort_t* __restrict__ qh, const ushort_t* __restrict__ kh,
    const ushort_t* __restrict__ vt, const float* __restrict__ bias,
    ushort_t* __restrict__ aoh) {
  __shared__ ushort_t plds[4][4096];       // fragment-linear P, per wave
  __shared__ float blds[64*68];            // pitch 68 -> only free 2-way conflicts
  const int tid = threadIdx.x, w = tid >> 6, lane = tid & 63;
  const int g = lane >> 4, l15 = lane & 15;
  const int h = blockIdx.x & 15;
  const int b = (blockIdx.x >> 4)*4 + w;   // 392 b-groups x 16 heads
  const size_t base = (size_t)(b*16 + h) * 2048;

  s16x8 qf[4], kf[4];
  #pragma unroll
  for (int t = 0; t < 4; t++) {
    size_t o = base + (size_t)(t*16 + l15)*32 + g*8;
    qf[t] = *(const s16x8*)&qh[o];
    kf[t] = *(const s16x8*)&kh[o];
  }
  s16x8 vf[2][2];
  #pragma unroll
  for (int kt = 0; kt < 2; kt++)
    #pragma unroll
    for (int nt = 0; nt < 2; nt++)
      vf[kt][nt] = *(const s16x8*)&vt[base + (size_t)(nt*16 + l15)*64 + kt*32 + g*8];

  const float* bh_ = bias + ((size_t)h << 12);
  #pragma unroll
  for (int it = 0; it < 4; it++) {
    int idx = it*1024 + tid*4;
    int rr = idx >> 6, cc = idx & 63;
    *(f32x4*)&blds[rr*68 + cc] = *(const f32x4*)&bh_[idx];
  }
  __syncthreads();

  f32x4 s[4][4];
  #pragma unroll
  for (int r = 0; r < 4; r++)
    #pragma unroll
    for (int c = 0; c < 4; c++) s[r][c] = (f32x4){0.f,0.f,0.f,0.f};
  #pragma unroll
  for (int r = 0; r < 4; r++)
    #pragma unroll
    for (int c = 0; c < 4; c++)
      s[r][c] = __builtin_amdgcn_mfma_f32_16x16x32_bf16(qf[r], kf[c], s[r][c], 0, 0, 0);

  const float invs = 0.17677669529663687f;  // 1/sqrt(32)
  #pragma unroll
  for (int r = 0; r < 4; r++)
    #pragma unroll
    for (int c = 0; c < 4; c++)
      #pragma unroll
      for (int j = 0; j < 4; j++) {
        int rr = r*16 + g*4 + j, cc = c*16 + l15;
        s[r][c][j] = s[r][c][j]*invs + blds[rr*68 + cc];
      }

  #pragma unroll
  for (int r = 0; r < 4; r++)
    #pragma unroll
    for (int j = 0; j < 4; j++) {
      float mx = fmaxf(fmaxf(s[r][0][j], s[r][1][j]), fmaxf(s[r][2][j], s[r][3][j]));
      mx = fmaxf(mx, __shfl_xor(mx, 1));
      mx = fmaxf(mx, __shfl_xor(mx, 2));
      mx = fmaxf(mx, __shfl_xor(mx, 4));
      mx = fmaxf(mx, __shfl_xor(mx, 8));
      float p0 = __expf(s[r][0][j]-mx), p1 = __expf(s[r][1][j]-mx);
      float p2 = __expf(s[r][2][j]-mx), p3 = __expf(s[r][3][j]-mx);
      float sum = p0 + p1 + p2 + p3;
      sum += __shfl_xor(sum, 1);
      sum += __shfl_xor(sum, 2);
      sum += __shfl_xor(sum, 4);
      sum += __shfl_xor(sum, 8);
      float rv = 1.0f / sum;
      s[r][0][j] = p0*rv; s[r][1][j] = p1*rv; s[r][2][j] = p2*rv; s[r][3][j] = p3*rv;
    }

  ushort_t* Pw = plds[w];
  asm volatile("s_waitcnt lgkmcnt(0)" ::: "memory");
  __builtin_amdgcn_sched_barrier(0);
  #pragma unroll
  for (int r = 0; r < 4; r++)
    #pragma unroll
    for (int c = 0; c < 4; c++)
      #pragma unroll
      for (int j = 0; j < 4; j++) {
        int idx = ((c >> 1)*4 + r)*512 + ((((c & 1)*2) + (l15 >> 3))*16 + g*4 + j)*8 + (l15 & 7);
        Pw[idx] = f2bf(s[r][c][j]);
      }
  asm volatile("s_waitcnt lgkmcnt(0)" ::: "memory");
  __builtin_amdgcn_sched_barrier(0);

  s16x8 pf[4][2];
  #pragma unroll
  for (int ta = 0; ta < 4; ta++)
    #pragma unroll
    for (int kt = 0; kt < 2; kt++)
      pf[ta][kt] = *(const s16x8*)&Pw[(kt*4 + ta)*512 + lane*8];

  f32x4 o[4][2];
  #pragma unroll
  for (int ta = 0; ta < 4; ta++)
    #pragma unroll
    for (int nt = 0; nt < 2; nt++) o[ta][nt] = (f32x4){0.f,0.f,0.f,0.f};
  #pragma unroll
  for (int ta = 0; ta < 4; ta++)
    #pragma unroll
    for (int nt = 0; nt < 2; nt++)
      #pragma unroll
      for (int kt = 0; kt < 2; kt++)
        o[ta][nt] = __builtin_amdgcn_mfma_f32_16x16x32_bf16(pf[ta][kt], vf[kt][nt], o[ta][nt], 0, 0, 0);

  #pragma unroll
  for (int ta = 0; ta < 4; ta++)
    #pragma unroll
    for (int nt = 0; nt < 2; nt++)
      #pragma unroll
      for (int j = 0; j < 4; j++) {
        int rr = ta*16 + g*4 + j, dd = nt*16 + l15;
        aoh[((size_t)b*64 + rr)*512 + h*32 + dd] = f2bf(o[ta][nt][j]);
      }
}

extern "C" void kernel_launch(void* const* d_in, const int* in_sizes, int n_in,
                              void* d_out, int out_size, void* d_ws, size_t ws_size,
                              hipStream_t stream) {
  const float* x      = (const float*)d_in[0];
  const float* qkv_w  = (const float*)d_in[1];
  const float* table  = (const float*)d_in[2];
  const float* proj_w = (const float*)d_in[3];
  const float* proj_b = (const float*)d_in[4];
  const int*   rel_idx = (const int*)d_in[5];

  const size_t S1 = S1_ELEMS;
  const size_t need = (4*S1 + 786432 + 262144)*sizeof(ushort_t) + 65536*sizeof(float);
  if (ws_size < need) return;

  ushort_t* qh  = (ushort_t*)d_ws;
  ushort_t* kh  = qh + S1;
  ushort_t* vt  = kh + S1;
  ushort_t* xh  = vt + S1;        // reused as attention-out after QKV GEMM
  ushort_t* wqh = xh + S1;
  ushort_t* wph = wqh + 786432;
  float*    bias = (float*)(wph + 262144);
  ushort_t* aoh = xh;

  hipFuncSetAttribute((const void*)k_gemm_qkv,
                      hipFuncAttributeMaxDynamicSharedMemorySize, 131072);
  hipFuncSetAttribute((const void*)k_gemm_proj,
                      hipFuncAttributeMaxDynamicSharedMemorySize, 73728);

  k_prep<<<3712, 256, 0, stream>>>(x, xh, qkv_w, wqh, proj_w, wph, table, rel_idx, bias);
  k_gemm_qkv<<<2352, 512, 131072, stream>>>(xh, wqh, qh, kh, vt);
  k_attn<<<6272, 256, 0, stream>>>(qh, kh, vt, bias, aoh);
  k_gemm_proj<<<1568, 512, 73728, stream>>>(aoh, wph, proj_b, (float*)d_out);
}